// Round 3
// baseline (151.433 us; speedup 1.0000x reference)
//
#include <hip/hip_runtime.h>

#define B_ 16
#define C_ 306
#define CP_ 320
#define T_ 4000
#define M_ 128

typedef short bf16x8 __attribute__((ext_vector_type(8)));
typedef float f32x4 __attribute__((ext_vector_type(4)));

// ---------- Kernel A: gate MLP -> w_hi/w_lo [B][M][CP_] bf16 + scale[B][M] ----
// one block per (b, 4 m's); 320 threads (c = tid)
__global__ __launch_bounds__(320)
void gate_kernel(const float* __restrict__ positions,   // [B,C,2]
                 const float* __restrict__ target,      // [M,2]
                 const float* __restrict__ w1,          // [3,32]
                 const float* __restrict__ b1,          // [32]
                 const float* __restrict__ w2,          // [32]
                 const float* __restrict__ b2,          // [1]
                 unsigned short* __restrict__ w_hi,     // [B,M,CP_]
                 unsigned short* __restrict__ w_lo,     // [B,M,CP_]
                 float* __restrict__ scale) {           // [B,M]
    const int b  = blockIdx.x >> 5;     // 512 blocks = B * 32
    const int mg = blockIdx.x & 31;     // group of 4 m
    const int tid = threadIdx.x;        // 0..319

    __shared__ float s_w1[96], s_b1[32], s_w2[32];
    __shared__ float2 s_pos[C_];
    __shared__ float s_b2;
    __shared__ float s_tgt[8];
    __shared__ float s_part[5];

    if (tid < 96) s_w1[tid] = w1[tid];
    if (tid < 32) { s_b1[tid] = b1[tid]; s_w2[tid] = w2[tid]; }
    if (tid == 256) s_b2 = b2[0];
    if (tid < C_) s_pos[tid] = ((const float2*)positions)[b * C_ + tid];
    if (tid >= 312) s_tgt[tid - 312] = target[mg * 8 + (tid - 312)];
    __syncthreads();

    float px = 0.0f, py = 0.0f;
    if (tid < C_) { px = s_pos[tid].x; py = s_pos[tid].y; }

#pragma unroll
    for (int mi = 0; mi < 4; ++mi) {
        float w = 0.0f;
        if (tid < C_) {
            const float dx = px - s_tgt[mi * 2 + 0];
            const float dy = py - s_tgt[mi * 2 + 1];
            const float d2 = dx * dx + dy * dy;
            // s2 = exp(-3.125 d2); s1 = s2^4; s0 = s1^4  (sigma chain x4)
            const float s2 = __expf(-d2 * 3.125f);
            const float q  = s2 * s2;
            const float s1 = q * q;
            const float r  = s1 * s1;
            const float s0 = r * r;
            float acc = s_b2;
#pragma unroll
            for (int j = 0; j < 32; ++j) {
                float h = fmaf(s0, s_w1[j],
                          fmaf(s1, s_w1[32 + j],
                          fmaf(s2, s_w1[64 + j], s_b1[j])));
                acc = fmaf(fmaxf(h, 0.0f), s_w2[j], acc);
            }
            w = acc;
        }

        // block-wide sum
        float s = w;
#pragma unroll
        for (int off = 32; off > 0; off >>= 1) s += __shfl_down(s, off, 64);
        if ((tid & 63) == 0) s_part[tid >> 6] = s;
        __syncthreads();
        if (tid == 0) {
            float tot = s_part[0] + s_part[1] + s_part[2] + s_part[3] + s_part[4];
            scale[b * M_ + mg * 4 + mi] = 1.0f / (tot + 1e-8f);
        }
        __syncthreads();   // protect s_part before next mi overwrites

        // split into bf16 hi (truncate) + lo
        const unsigned int u = __float_as_uint(w);
        const unsigned short h = (unsigned short)(u >> 16);
        const float lof = w - __uint_as_float(u & 0xffff0000u);
        const unsigned short l = (unsigned short)(__float_as_uint(lof) >> 16);
        const size_t off = (size_t)(b * M_ + mg * 4 + mi) * CP_ + tid;
        w_hi[off] = h;
        w_lo[off] = l;
    }
}

// ---------- Kernel B: MFMA GEMM  out[b][m][t] = scale[b][m] * sum_c w*x ------
// block tile: m = 128, t = 128; 4 waves of 64x64; BK = 64 (2 sub-steps of 32)
// W fragments load directly from global (L2-resident); only X goes through LDS.
__global__ __launch_bounds__(256, 3)
void merge_gemm(const float* __restrict__ x,            // [B,C,T]
                const unsigned short* __restrict__ w_hi,// [B,M,CP_]
                const unsigned short* __restrict__ w_lo,
                const float* __restrict__ scale,        // [B,M]
                float* __restrict__ out) {              // [B,M,T]
    const int t0 = blockIdx.x * 128;
    const int b  = blockIdx.y;
    const int tid  = threadIdx.x;
    const int lane = tid & 63;
    const int wv   = tid >> 6;
    const int tquad = lane >> 4;   // 0..3
    const int tsub  = lane & 15;   // 0..15

    // X tiles in LDS: [8 c-runs][128 t][8 halfs] = 16 KB each
    __shared__ __align__(16) unsigned short sXh[8192];
    __shared__ __align__(16) unsigned short sXl[8192];
    __shared__ __align__(16) float sScale[M_];

    if (tid < M_) sScale[tid] = scale[b * M_ + tid];

    const float* xb = x + (size_t)b * C_ * T_;
    const unsigned short* whB = w_hi + (size_t)b * M_ * CP_;
    const unsigned short* wlB = w_lo + (size_t)b * M_ * CP_;

    f32x4 acc[4][4];
#pragma unroll
    for (int i = 0; i < 4; ++i)
#pragma unroll
        for (int j = 0; j < 4; ++j) acc[i][j] = (f32x4){0.f, 0.f, 0.f, 0.f};

    const int mw = (wv & 1) * 64;    // wave m-origin
    const int tw = (wv >> 1) * 64;   // wave t-origin

    for (int step = 0; step < CP_ / 64; ++step) {
        const int c0 = step * 64;

        // ---- stage X tile transposed: [8 r][128 t][8], split fp32 -> hi/lo
#pragma unroll
        for (int s = 0; s < 2; ++s) {
            const int t = wv * 16 + tsub + s * 64;          // 0..127
            const int tg = min(t0 + t, T_ - 1);
            const float* xcol = xb + tg;
#pragma unroll
            for (int k = 0; k < 8; ++k) {
                const int p = tquad + 4 * k;                // c-pair 0..31
                const int c = c0 + 2 * p;
                const int ca = min(c, C_ - 1);
                const int cb = min(c + 1, C_ - 1);
                const float xa = xcol[(size_t)ca * T_];
                const float xv = xcol[(size_t)cb * T_];
                const unsigned int ua = __float_as_uint(xa);
                const unsigned int ub = __float_as_uint(xv);
                const unsigned int hp = (ua >> 16) | (ub & 0xffff0000u);
                const float la = xa - __uint_as_float(ua & 0xffff0000u);
                const float lb = xv - __uint_as_float(ub & 0xffff0000u);
                const unsigned int lp = (__float_as_uint(la) >> 16) |
                                        (__float_as_uint(lb) & 0xffff0000u);
                const int off32 = (p >> 2) * 512 + t * 4 + (p & 3);
                ((unsigned int*)sXh)[off32] = hp;
                ((unsigned int*)sXl)[off32] = lp;
            }
        }
        __syncthreads();

        // ---- two k-substeps of 32
#pragma unroll
        for (int ks = 0; ks < 2; ++ks) {
            const int cb0 = c0 + ks * 32;

            bf16x8 bh[4], bl[4];
#pragma unroll
            for (int i = 0; i < 4; ++i) {
                const int toff = ((ks * 4 + tquad) * 128 + tw + i * 16 + tsub) * 8;
                bh[i] = *(const bf16x8*)(sXh + toff);
                bl[i] = *(const bf16x8*)(sXl + toff);
            }
#pragma unroll
            for (int mi = 0; mi < 4; ++mi) {
                const size_t woff = (size_t)(mw + mi * 16 + tsub) * CP_ + cb0 + tquad * 8;
                const bf16x8 ah = *(const bf16x8*)(whB + woff);
                const bf16x8 al = *(const bf16x8*)(wlB + woff);
#pragma unroll
                for (int ti = 0; ti < 4; ++ti) {
                    acc[mi][ti] = __builtin_amdgcn_mfma_f32_16x16x32_bf16(
                        ah, bh[ti], acc[mi][ti], 0, 0, 0);
                    acc[mi][ti] = __builtin_amdgcn_mfma_f32_16x16x32_bf16(
                        ah, bl[ti], acc[mi][ti], 0, 0, 0);
                    acc[mi][ti] = __builtin_amdgcn_mfma_f32_16x16x32_bf16(
                        al, bh[ti], acc[mi][ti], 0, 0, 0);
                }
            }
        }
        __syncthreads();
    }

    // ---- epilogue: fold scale, store (C/D: col = lane&15, row = quad*4+reg)
#pragma unroll
    for (int mi = 0; mi < 4; ++mi) {
        const int mbase = mw + mi * 16 + tquad * 4;
        const float4 sc = *(const float4*)(sScale + mbase);
#pragma unroll
        for (int ti = 0; ti < 4; ++ti) {
            const int tg = t0 + tw + ti * 16 + tsub;
            if (tg < T_) {
                float* op = out + ((size_t)b * M_ + mbase) * T_ + tg;
                op[0 * T_] = acc[mi][ti][0] * sc.x;
                op[1 * T_] = acc[mi][ti][1] * sc.y;
                op[2 * T_] = acc[mi][ti][2] * sc.z;
                op[3 * T_] = acc[mi][ti][3] * sc.w;
            }
        }
    }
}

extern "C" void kernel_launch(void* const* d_in, const int* in_sizes, int n_in,
                              void* d_out, int out_size, void* d_ws, size_t ws_size,
                              hipStream_t stream) {
    const float* x         = (const float*)d_in[0];
    const float* positions = (const float*)d_in[1];
    const float* target    = (const float*)d_in[2];
    const float* w1        = (const float*)d_in[3];
    const float* b1        = (const float*)d_in[4];
    const float* w2        = (const float*)d_in[5];
    const float* b2        = (const float*)d_in[6];
    float* out = (float*)d_out;

    unsigned short* w_hi = (unsigned short*)d_ws;                 // B*M*CP halfs
    unsigned short* w_lo = w_hi + (size_t)B_ * M_ * CP_;
    float* scale = (float*)(w_lo + (size_t)B_ * M_ * CP_);        // B*M floats

    gate_kernel<<<B_ * 32, 320, 0, stream>>>(positions, target, w1, b1, w2, b2,
                                             w_hi, w_lo, scale);

    dim3 grid((T_ + 127) / 128, B_);
    merge_gemm<<<grid, 256, 0, stream>>>(x, w_hi, w_lo, scale, out);
}